// Round 9
// baseline (196.294 us; speedup 1.0000x reference)
//
#include <hip/hip_runtime.h>
#include <hip/hip_bf16.h>
#include <cstdint>
#include <cstddef>

#define BS 8
#define SEQ 1024
#define DMODEL 512
#define NHEADS 8
#define DHEAD 64
#define QBLK 16
#define PPAD 1032   // P bf16 row stride (elems): 16B-aligned; 129 16B-blocks/row == 1 mod 8 -> even b128 spread

typedef float f32x4 __attribute__((ext_vector_type(4)));
typedef short bf16x8 __attribute__((ext_vector_type(8)));

static __device__ __forceinline__ unsigned short f2bf(float v) {
    __hip_bfloat16 hb = __float2bfloat16(v);
    return *reinterpret_cast<unsigned short*>(&hb);
}

// ---------------------------------------------------------------------------
// f32 -> bf16 conversion pre-pass (7 independent jobs, blockIdx.y selects)
// ---------------------------------------------------------------------------
struct CvtJob { const float* s; unsigned short* d; int n4; };

__global__ __launch_bounds__(256) void cvt_many(
    CvtJob j0, CvtJob j1, CvtJob j2, CvtJob j3, CvtJob j4, CvtJob j5, CvtJob j6)
{
    CvtJob j;
    switch (blockIdx.y) {
        case 0: j = j0; break; case 1: j = j1; break; case 2: j = j2; break;
        case 3: j = j3; break; case 4: j = j4; break; case 5: j = j5; break;
        default: j = j6; break;
    }
    for (int i = blockIdx.x * 256 + threadIdx.x; i < j.n4; i += gridDim.x * 256) {
        const float4 f = ((const float4*)j.s)[i];
        uint2 u;
        u.x = (unsigned)f2bf(f.x) | ((unsigned)f2bf(f.y) << 16);
        u.y = (unsigned)f2bf(f.z) | ((unsigned)f2bf(f.w) << 16);
        ((uint2*)j.d)[i] = u;
    }
}

// ---------------------------------------------------------------------------
// bf16 MFMA GEMM, tile 64M x 128N, BK=64, global_load_lds staging with
// XOR source-swizzle (chunk c8 ^= r&7). Validated r6/r7 — unchanged.
// ---------------------------------------------------------------------------
struct GArgs { const unsigned short* A; const unsigned short* W;
               const float* bias; void* C; float scale; int mode; };

__global__ __launch_bounds__(256) void gemm_mfma(GArgs g0, GArgs g1, GArgs g2) {
    __shared__ __align__(16) unsigned short As[64 * 64];
    __shared__ __align__(16) unsigned short Bs[128 * 64];

    const GArgs g = (blockIdx.z == 0) ? g0 : ((blockIdx.z == 1) ? g1 : g2);
    const int tid = threadIdx.x;
    const int w = tid >> 6, l = tid & 63, lr = l & 15, lg = l >> 4;
    const int bm = blockIdx.y * 64, bn = blockIdx.x * 128;
    const int mrow = (w & 1) * 32, ncol = (w >> 1) * 64;

    f32x4 acc[2][4];
#pragma unroll
    for (int mt = 0; mt < 2; ++mt)
#pragma unroll
        for (int nt = 0; nt < 4; ++nt) acc[mt][nt] = (f32x4)0.f;

    for (int k0 = 0; k0 < DMODEL; k0 += 64) {
#pragma unroll
        for (int i = 0; i < 2; ++i) {
            const int rbase = i * 32 + w * 8;
            const int r = rbase + (l >> 3);
            const unsigned short* src = g.A + (size_t)(bm + r) * DMODEL + k0
                                        + 8 * ((l & 7) ^ (r & 7));
            __builtin_amdgcn_global_load_lds((const unsigned int*)src,
                                             (unsigned int*)&As[rbase * 64], 16, 0, 0);
        }
#pragma unroll
        for (int i = 0; i < 4; ++i) {
            const int rbase = i * 32 + w * 8;
            const int r = rbase + (l >> 3);
            const unsigned short* src = g.W + (size_t)(bn + r) * DMODEL + k0
                                        + 8 * ((l & 7) ^ (r & 7));
            __builtin_amdgcn_global_load_lds((const unsigned int*)src,
                                             (unsigned int*)&Bs[rbase * 64], 16, 0, 0);
        }
        __syncthreads();
#pragma unroll
        for (int kk = 0; kk < 2; ++kk) {
            bf16x8 av[2], bv[4];
#pragma unroll
            for (int mt = 0; mt < 2; ++mt) {
                const int ra = mrow + mt * 16 + lr;
                av[mt] = *(const bf16x8*)&As[ra * 64 + 8 * ((kk * 4 + lg) ^ (ra & 7))];
            }
#pragma unroll
            for (int nt = 0; nt < 4; ++nt) {
                const int rb = ncol + nt * 16 + lr;
                bv[nt] = *(const bf16x8*)&Bs[rb * 64 + 8 * ((kk * 4 + lg) ^ (rb & 7))];
            }
#pragma unroll
            for (int mt = 0; mt < 2; ++mt)
#pragma unroll
                for (int nt = 0; nt < 4; ++nt)
                    acc[mt][nt] = __builtin_amdgcn_mfma_f32_16x16x32_bf16(
                        av[mt], bv[nt], acc[mt][nt], 0, 0, 0);
        }
        __syncthreads();
    }

    if (g.mode == 0) {
        float* C = (float*)g.C;
#pragma unroll
        for (int mt = 0; mt < 2; ++mt)
#pragma unroll
        for (int nt = 0; nt < 4; ++nt)
#pragma unroll
        for (int j = 0; j < 4; ++j) {
            const int r = bm + mrow + mt * 16 + lg * 4 + j;
            const int c = bn + ncol + nt * 16 + lr;
            C[(size_t)r * DMODEL + c] = acc[mt][nt][j] * g.scale
                                        + (g.bias ? g.bias[c] : 0.f);
        }
    } else if (g.mode == 1) {
        unsigned short* C = (unsigned short*)g.C;
#pragma unroll
        for (int mt = 0; mt < 2; ++mt)
#pragma unroll
        for (int nt = 0; nt < 4; ++nt)
#pragma unroll
        for (int j = 0; j < 4; ++j) {
            const int r = bm + mrow + mt * 16 + lg * 4 + j;
            const int c = bn + ncol + nt * 16 + lr;
            const float v = acc[mt][nt][j] * g.scale + (g.bias ? g.bias[c] : 0.f);
            const int b = r >> 10, ll = r & (SEQ - 1);
            const int h = c >> 6, dd = c & 63;
            C[((size_t)(b * NHEADS + h) * SEQ + ll) * DHEAD + dd] = f2bf(v);
        }
    } else {
        unsigned short* C = (unsigned short*)g.C;
#pragma unroll
        for (int mt = 0; mt < 2; ++mt)
#pragma unroll
        for (int nt = 0; nt < 4; ++nt) {
            const int c = bn + ncol + nt * 16 + lr;
            const int h = c >> 6, dd = c & 63;
            const int r0 = bm + mrow + mt * 16 + lg * 4;
            const int b = r0 >> 10, l0 = r0 & (SEQ - 1);
            unsigned short tmp[4];
#pragma unroll
            for (int j = 0; j < 4; ++j)
                tmp[j] = f2bf(acc[mt][nt][j] * g.scale + (g.bias ? g.bias[c] : 0.f));
            uint2 u;
            u.x = (unsigned)tmp[0] | ((unsigned)tmp[1] << 16);
            u.y = (unsigned)tmp[2] | ((unsigned)tmp[3] << 16);
            *(uint2*)&C[((size_t)(b * NHEADS + h) * DHEAD + dd) * SEQ + l0] = u;
        }
    }
}

// ---------------------------------------------------------------------------
// MFMA sparsemax attention, SWAPPED QK^T: acc[t] = mfma(K,Q) so each lane
// owns ONE q-row (lr) x 64 keys. Newton tau on candidate-compacted lists.
// r8 BUGFIX: the candidate list spans ALL 4 waves, so each wave's reduced
// list-sum is already the row total — the cross-wave LDS combine applies
// ONLY to the full-scan fallback path (per-wave partial key slices).
// ---------------------------------------------------------------------------
__global__ __launch_bounds__(256, 4) void attn_mfma(
    const unsigned short* __restrict__ Q, const unsigned short* __restrict__ K,
    const unsigned short* __restrict__ Vt, unsigned short* __restrict__ R)
{
    __shared__ __align__(16) unsigned short P[QBLK][PPAD];     // 33 KB
    __shared__ __align__(16) float clist[QBLK][68];            // 4.4 KB candidate lists
    __shared__ int cnt_s[QBLK];
    __shared__ __align__(16) float red_m[QBLK][4];             // [row][wave]
    __shared__ __align__(16) float red_s[2][QBLK][4];
    __shared__ __align__(16) float red_c[2][QBLK][4];

    const int tid = threadIdx.x;
    const int w = tid >> 6, l = tid & 63, lr = l & 15, lg = l >> 4;

    // XCD-aware decode: xcd = flat&7 owns 512 consecutive nids (8 (b,h) pairs)
    const int flat = blockIdx.x;
    const int nid = (flat & 7) * 512 + (flat >> 3);
    const int q0 = (nid & 63) * QBLK;
    const int h = (nid >> 6) & (NHEADS - 1);
    const int b = nid >> 9;

    const size_t base = (size_t)(b * NHEADS + h) * SEQ * DHEAD;
    const unsigned short* Qp = Q + base;
    const unsigned short* Kp = K + base;

    const int ks = w * 256;   // wave's key slice

    // ---- swapped QK^T: A=K rows (keys), B=Q rows (q); Q pre-scaled 1/8 ----
    const bf16x8 aq0 = *(const bf16x8*)(Qp + (size_t)(q0 + lr) * DHEAD + lg * 8);
    const bf16x8 aq1 = *(const bf16x8*)(Qp + (size_t)(q0 + lr) * DHEAD + 32 + lg * 8);
    f32x4 acc[16];
#pragma unroll
    for (int t = 0; t < 16; ++t) acc[t] = (f32x4)0.f;
#pragma unroll
    for (int t = 0; t < 16; ++t) {
        const unsigned short* kp = Kp + (size_t)(ks + t * 16 + lr) * DHEAD + lg * 8;
        const bf16x8 bk0 = *(const bf16x8*)(kp);
        const bf16x8 bk1 = *(const bf16x8*)(kp + 32);
        acc[t] = __builtin_amdgcn_mfma_f32_16x16x32_bf16(bk0, aq0, acc[t], 0, 0, 0);
        acc[t] = __builtin_amdgcn_mfma_f32_16x16x32_bf16(bk1, aq1, acc[t], 0, 0, 0);
    }
    // lane (lr,lg) holds S[q-row q0+lr][key ks + t*16 + lg*4 + j]

    // ---- per-lane row max over 64 values, then lg-reduce (2 shfl stages) ----
    f32x4 m4 = acc[0];
#pragma unroll
    for (int t = 1; t < 16; ++t) {
        m4[0] = fmaxf(m4[0], acc[t][0]); m4[1] = fmaxf(m4[1], acc[t][1]);
        m4[2] = fmaxf(m4[2], acc[t][2]); m4[3] = fmaxf(m4[3], acc[t][3]);
    }
    float m = fmaxf(fmaxf(m4[0], m4[1]), fmaxf(m4[2], m4[3]));
    m = fmaxf(m, __shfl_xor(m, 16));
    m = fmaxf(m, __shfl_xor(m, 32));
    if (lg == 0) red_m[lr][w] = m;

    // clear candidate lists + counters (all threads)
    for (int i = tid; i < QBLK * 68; i += 256) (&clist[0][0])[i] = -3.0e38f;
    if (tid < QBLK) cnt_s[tid] = 0;
    __syncthreads();

    // block row max -> tau0 = max - 1 (f(tau0) >= 0, monotone Newton from below)
    const float4 rm4 = *(const float4*)red_m[lr];
    const float rmax = fmaxf(fmaxf(rm4.x, rm4.y), fmaxf(rm4.z, rm4.w));
    float tau = rmax - 1.0f;
    const float thr = tau;   // support is always a subset of {z > rowmax-1}

    // ---- candidate compaction (LDS atomics; cap 64/row, overflow->fallback) ----
#pragma unroll
    for (int t = 0; t < 16; ++t)
#pragma unroll
        for (int j = 0; j < 4; ++j) {
            const float z = acc[t][j];
            if (z > thr) {
                const int pos = atomicAdd(&cnt_s[lr], 1);
                if (pos < 64) clist[lr][pos] = z;
            }
        }
    __syncthreads();

    const bool full = (cnt_s[lr] > 64);   // per-row fallback flag (rare/adversarial)
    // load this lane's candidate share (16 slots, -inf padded)
    const f32x4* clp = (const f32x4*)&clist[lr][lg * 16];
    const f32x4 cd0 = clp[0], cd1 = clp[1], cd2 = clp[2], cd3 = clp[3];

    // ---- Newton on tau: 1 barrier/iter (dbuf), tol break ----
    for (int it = 0; it < 16; ++it) {
        const int bb = (it + 1) & 1;
        float s = 0.f, c = 0.f;
        if (!full) {
#pragma unroll
            for (int i = 0; i < 4; ++i) {
                const float z0 = cd0[i], z1 = cd1[i], z2 = cd2[i], z3 = cd3[i];
                if (z0 > tau) { s += z0; c += 1.f; }
                if (z1 > tau) { s += z1; c += 1.f; }
                if (z2 > tau) { s += z2; c += 1.f; }
                if (z3 > tau) { s += z3; c += 1.f; }
            }
        } else {
#pragma unroll
            for (int t = 0; t < 16; ++t)
#pragma unroll
                for (int j = 0; j < 4; ++j) {
                    const float z = acc[t][j];
                    if (z > tau) { s += z; c += 1.f; }
                }
        }
        // reduce across the 4 lg-groups of this wave
        s += __shfl_xor(s, 16); c += __shfl_xor(c, 16);
        s += __shfl_xor(s, 32); c += __shfl_xor(c, 32);
        if (lg == 0) { red_s[bb][lr][w] = s; red_c[bb][lr][w] = c; }
        __syncthreads();
        // !full: clist spans all waves -> wave-local reduced sum IS the row
        // total (all waves compute it identically). full: per-wave partial
        // key-slice sums must be combined across waves via LDS.
        float st, ct;
        if (full) {
            const float4 s4 = *(const float4*)red_s[bb][lr];
            const float4 c4 = *(const float4*)red_c[bb][lr];
            st = (s4.x + s4.y) + (s4.z + s4.w);
            ct = (c4.x + c4.y) + (c4.z + c4.w);
        } else {
            st = s;
            ct = c;
        }
        const float tn = (st - 1.f) / ct;   // ct >= 1 always (tau < row max)
        float delta = tn - tau;
        tau = tn;
        // block-uniform convergence: max over the 16 rows (lr bits)
        delta = fmaxf(delta, __shfl_xor(delta, 1));
        delta = fmaxf(delta, __shfl_xor(delta, 2));
        delta = fmaxf(delta, __shfl_xor(delta, 4));
        delta = fmaxf(delta, __shfl_xor(delta, 8));
        if (delta < 1e-5f) break;   // uniform across waves (same reduced values)
    }

    // ---- P = relu(acc - tau) -> bf16 LDS, pair-packed b32 writes ----
#pragma unroll
    for (int t = 0; t < 16; ++t)
#pragma unroll
        for (int jp = 0; jp < 2; ++jp) {
            const unsigned lo = f2bf(fmaxf(acc[t][2 * jp] - tau, 0.f));
            const unsigned hi = f2bf(fmaxf(acc[t][2 * jp + 1] - tau, 0.f));
            *(unsigned*)&P[lr][ks + t * 16 + lg * 4 + 2 * jp] = lo | (hi << 16);
        }
    __syncthreads();   // P complete — last barrier

    // ---- PV: wave w owns d-cols w*16..+15; V from global Vt, depth-4 ring ----
    const int dcol = w * 16;
    const unsigned short* VtP = Vt + ((size_t)(b * NHEADS + h) * DHEAD + dcol + lr) * SEQ
                                + lg * 8;
    f32x4 o = (f32x4)0.f;
    bf16x8 vb0 = *(const bf16x8*)(VtP + 0 * 32);
    bf16x8 vb1 = *(const bf16x8*)(VtP + 1 * 32);
    bf16x8 vb2 = *(const bf16x8*)(VtP + 2 * 32);
    bf16x8 vb3 = *(const bf16x8*)(VtP + 3 * 32);
#define PV_STEP(KT, VREG)                                                      \
    {                                                                          \
        const bf16x8 pa = *(const bf16x8*)&P[lr][(KT) * 32 + lg * 8];          \
        __builtin_amdgcn_s_setprio(1);                                         \
        o = __builtin_amdgcn_mfma_f32_16x16x32_bf16(pa, VREG, o, 0, 0, 0);     \
        __builtin_amdgcn_s_setprio(0);                                         \
        if ((KT) + 4 < 32) VREG = *(const bf16x8*)(VtP + ((KT) + 4) * 32);     \
    }
    for (int kt = 0; kt < 32; kt += 4) {
        PV_STEP(kt + 0, vb0)
        PV_STEP(kt + 1, vb1)
        PV_STEP(kt + 2, vb2)
        PV_STEP(kt + 3, vb3)
    }
#undef PV_STEP

    // ---- write O tile rows q0+lg*4+j, cols h*64+dcol+lr (bf16 for final GEMM)
#pragma unroll
    for (int j = 0; j < 4; ++j)
        R[((size_t)b * SEQ + q0 + lg * 4 + j) * DMODEL + h * DHEAD + dcol + lr] =
            f2bf(o[j]);
}

extern "C" void kernel_launch(void* const* d_in, const int* in_sizes, int n_in,
                              void* d_out, int out_size, void* d_ws, size_t ws_size,
                              hipStream_t stream) {
    const float* h_q = (const float*)d_in[0];
    const float* h_k = (const float*)d_in[1];
    const float* h_v = (const float*)d_in[2];
    const float* Wq  = (const float*)d_in[3];
    const float* Wk  = (const float*)d_in[4];
    const float* Wv  = (const float*)d_in[5];
    const float* bv  = (const float*)d_in[6];
    const float* Wf  = (const float*)d_in[7];
    const float* bf  = (const float*)d_in[8];
    float* out = (float*)d_out;

    const size_t perT = (size_t)BS * SEQ * DMODEL;   // 4,194,304 elements
    const size_t wN = (size_t)DMODEL * DMODEL;       // 262,144 elements
    unsigned short* hq_b = (unsigned short*)d_ws;    // bf16 inputs
    unsigned short* hk_b = hq_b + perT;
    unsigned short* hv_b = hk_b + perT;
    unsigned short* Qws  = hv_b + perT;              // projections (head layout)
    unsigned short* Kws  = Qws + perT;
    unsigned short* Vtw  = Kws + perT;               // transposed [b][h][d][l]
    unsigned short* Rws  = Vtw + perT;               // attn output (bf16)
    unsigned short* Wqb  = Rws + perT;               // bf16 weights
    unsigned short* Wkb  = Wqb + wN;
    unsigned short* Wvb  = Wkb + wN;
    unsigned short* Wfb  = Wvb + wN;

    // 1) convert inputs + weights to bf16
    {
        CvtJob j0{h_q, hq_b, (int)(perT / 4)};
        CvtJob j1{h_k, hk_b, (int)(perT / 4)};
        CvtJob j2{h_v, hv_b, (int)(perT / 4)};
        CvtJob j3{Wq, Wqb, (int)(wN / 4)};
        CvtJob j4{Wk, Wkb, (int)(wN / 4)};
        CvtJob j5{Wv, Wvb, (int)(wN / 4)};
        CvtJob j6{Wf, Wfb, (int)(wN / 4)};
        cvt_many<<<dim3(512, 7), 256, 0, stream>>>(j0, j1, j2, j3, j4, j5, j6);
    }

    // 2) fused Q/K/V projections (bf16 MFMA, gload_lds staging)
    {
        GArgs gq{hq_b, Wqb, nullptr, Qws, 0.125f, 1};
        GArgs gk{hk_b, Wkb, nullptr, Kws, 1.0f, 1};
        GArgs gv{hv_b, Wvb, bv,      Vtw, 1.0f, 2};
        gemm_mfma<<<dim3(DMODEL / 128, BS * SEQ / 64, 3), 256, 0, stream>>>(gq, gk, gv);
    }

    // 3) attention
    attn_mfma<<<dim3(BS * NHEADS * (SEQ / QBLK)), 256, 0, stream>>>(Qws, Kws, Vtw, Rws);

    // 4) output projection
    {
        GArgs gf{Rws, Wfb, bf, out, 1.0f, 0};
        gemm_mfma<<<dim3(DMODEL / 128, BS * SEQ / 64, 1), 256, 0, stream>>>(gf, gf, gf);
    }
}

// Round 10
// 192.819 us; speedup vs baseline: 1.0180x; 1.0180x over previous
//
#include <hip/hip_runtime.h>
#include <hip/hip_bf16.h>
#include <cstdint>
#include <cstddef>

#define BS 8
#define SEQ 1024
#define DMODEL 512
#define NHEADS 8
#define DHEAD 64
#define QBLK 16
#define PPAD 1032   // P bf16 row stride (elems): 16B-aligned; 129 16B-blocks/row == 1 mod 8 -> even b128 spread

typedef float f32x4 __attribute__((ext_vector_type(4)));
typedef short bf16x8 __attribute__((ext_vector_type(8)));

static __device__ __forceinline__ unsigned short f2bf(float v) {
    __hip_bfloat16 hb = __float2bfloat16(v);
    return *reinterpret_cast<unsigned short*>(&hb);
}

// ---------------------------------------------------------------------------
// f32 -> bf16 conversion pre-pass (7 independent jobs, blockIdx.y selects)
// ---------------------------------------------------------------------------
struct CvtJob { const float* s; unsigned short* d; int n4; };

__global__ __launch_bounds__(256) void cvt_many(
    CvtJob j0, CvtJob j1, CvtJob j2, CvtJob j3, CvtJob j4, CvtJob j5, CvtJob j6)
{
    CvtJob j;
    switch (blockIdx.y) {
        case 0: j = j0; break; case 1: j = j1; break; case 2: j = j2; break;
        case 3: j = j3; break; case 4: j = j4; break; case 5: j = j5; break;
        default: j = j6; break;
    }
    for (int i = blockIdx.x * 256 + threadIdx.x; i < j.n4; i += gridDim.x * 256) {
        const float4 f = ((const float4*)j.s)[i];
        uint2 u;
        u.x = (unsigned)f2bf(f.x) | ((unsigned)f2bf(f.y) << 16);
        u.y = (unsigned)f2bf(f.z) | ((unsigned)f2bf(f.w) << 16);
        ((uint2*)j.d)[i] = u;
    }
}

// ---------------------------------------------------------------------------
// bf16 MFMA GEMM, tile 64M x 128N, BK=64, global_load_lds staging with
// XOR source-swizzle (chunk c8 ^= r&7). Validated r6/r7 — unchanged.
// ---------------------------------------------------------------------------
struct GArgs { const unsigned short* A; const unsigned short* W;
               const float* bias; void* C; float scale; int mode; };

__global__ __launch_bounds__(256) void gemm_mfma(GArgs g0, GArgs g1, GArgs g2) {
    __shared__ __align__(16) unsigned short As[64 * 64];
    __shared__ __align__(16) unsigned short Bs[128 * 64];

    const GArgs g = (blockIdx.z == 0) ? g0 : ((blockIdx.z == 1) ? g1 : g2);
    const int tid = threadIdx.x;
    const int w = tid >> 6, l = tid & 63, lr = l & 15, lg = l >> 4;
    const int bm = blockIdx.y * 64, bn = blockIdx.x * 128;
    const int mrow = (w & 1) * 32, ncol = (w >> 1) * 64;

    f32x4 acc[2][4];
#pragma unroll
    for (int mt = 0; mt < 2; ++mt)
#pragma unroll
        for (int nt = 0; nt < 4; ++nt) acc[mt][nt] = (f32x4)0.f;

    for (int k0 = 0; k0 < DMODEL; k0 += 64) {
#pragma unroll
        for (int i = 0; i < 2; ++i) {
            const int rbase = i * 32 + w * 8;
            const int r = rbase + (l >> 3);
            const unsigned short* src = g.A + (size_t)(bm + r) * DMODEL + k0
                                        + 8 * ((l & 7) ^ (r & 7));
            __builtin_amdgcn_global_load_lds((const unsigned int*)src,
                                             (unsigned int*)&As[rbase * 64], 16, 0, 0);
        }
#pragma unroll
        for (int i = 0; i < 4; ++i) {
            const int rbase = i * 32 + w * 8;
            const int r = rbase + (l >> 3);
            const unsigned short* src = g.W + (size_t)(bn + r) * DMODEL + k0
                                        + 8 * ((l & 7) ^ (r & 7));
            __builtin_amdgcn_global_load_lds((const unsigned int*)src,
                                             (unsigned int*)&Bs[rbase * 64], 16, 0, 0);
        }
        __syncthreads();
#pragma unroll
        for (int kk = 0; kk < 2; ++kk) {
            bf16x8 av[2], bv[4];
#pragma unroll
            for (int mt = 0; mt < 2; ++mt) {
                const int ra = mrow + mt * 16 + lr;
                av[mt] = *(const bf16x8*)&As[ra * 64 + 8 * ((kk * 4 + lg) ^ (ra & 7))];
            }
#pragma unroll
            for (int nt = 0; nt < 4; ++nt) {
                const int rb = ncol + nt * 16 + lr;
                bv[nt] = *(const bf16x8*)&Bs[rb * 64 + 8 * ((kk * 4 + lg) ^ (rb & 7))];
            }
#pragma unroll
            for (int mt = 0; mt < 2; ++mt)
#pragma unroll
                for (int nt = 0; nt < 4; ++nt)
                    acc[mt][nt] = __builtin_amdgcn_mfma_f32_16x16x32_bf16(
                        av[mt], bv[nt], acc[mt][nt], 0, 0, 0);
        }
        __syncthreads();
    }

    if (g.mode == 0) {
        float* C = (float*)g.C;
#pragma unroll
        for (int mt = 0; mt < 2; ++mt)
#pragma unroll
        for (int nt = 0; nt < 4; ++nt)
#pragma unroll
        for (int j = 0; j < 4; ++j) {
            const int r = bm + mrow + mt * 16 + lg * 4 + j;
            const int c = bn + ncol + nt * 16 + lr;
            C[(size_t)r * DMODEL + c] = acc[mt][nt][j] * g.scale
                                        + (g.bias ? g.bias[c] : 0.f);
        }
    } else if (g.mode == 1) {
        unsigned short* C = (unsigned short*)g.C;
#pragma unroll
        for (int mt = 0; mt < 2; ++mt)
#pragma unroll
        for (int nt = 0; nt < 4; ++nt)
#pragma unroll
        for (int j = 0; j < 4; ++j) {
            const int r = bm + mrow + mt * 16 + lg * 4 + j;
            const int c = bn + ncol + nt * 16 + lr;
            const float v = acc[mt][nt][j] * g.scale + (g.bias ? g.bias[c] : 0.f);
            const int b = r >> 10, ll = r & (SEQ - 1);
            const int h = c >> 6, dd = c & 63;
            C[((size_t)(b * NHEADS + h) * SEQ + ll) * DHEAD + dd] = f2bf(v);
        }
    } else {
        unsigned short* C = (unsigned short*)g.C;
#pragma unroll
        for (int mt = 0; mt < 2; ++mt)
#pragma unroll
        for (int nt = 0; nt < 4; ++nt) {
            const int c = bn + ncol + nt * 16 + lr;
            const int h = c >> 6, dd = c & 63;
            const int r0 = bm + mrow + mt * 16 + lg * 4;
            const int b = r0 >> 10, l0 = r0 & (SEQ - 1);
            unsigned short tmp[4];
#pragma unroll
            for (int j = 0; j < 4; ++j)
                tmp[j] = f2bf(acc[mt][nt][j] * g.scale + (g.bias ? g.bias[c] : 0.f));
            uint2 u;
            u.x = (unsigned)tmp[0] | ((unsigned)tmp[1] << 16);
            u.y = (unsigned)tmp[2] | ((unsigned)tmp[3] << 16);
            *(uint2*)&C[((size_t)(b * NHEADS + h) * DHEAD + dd) * SEQ + l0] = u;
        }
    }
}

// ---------------------------------------------------------------------------
// MFMA sparsemax attention, swapped QK^T (lane owns one q-row).
// r10: (a) K-fragment prefetch ring depth 4 (breaks load->MFMA serialization
// at low VGPR budget); (b) barrier-free Newton fast path — when no row's
// candidate list overflowed, every wave computes the IDENTICAL row-total from
// the shared list, so no cross-wave combine is needed; block-uniform __any
// selects the r9 barrier-synced full-scan fallback otherwise.
// ---------------------------------------------------------------------------
__global__ __launch_bounds__(256, 4) void attn_mfma(
    const unsigned short* __restrict__ Q, const unsigned short* __restrict__ K,
    const unsigned short* __restrict__ Vt, unsigned short* __restrict__ R)
{
    __shared__ __align__(16) unsigned short P[QBLK][PPAD];     // 33 KB
    __shared__ __align__(16) float clist[QBLK][68];            // 4.4 KB candidate lists
    __shared__ int cnt_s[QBLK];
    __shared__ __align__(16) float red_m[QBLK][4];             // [row][wave]
    __shared__ __align__(16) float red_s[2][QBLK][4];
    __shared__ __align__(16) float red_c[2][QBLK][4];

    const int tid = threadIdx.x;
    const int w = tid >> 6, l = tid & 63, lr = l & 15, lg = l >> 4;

    // XCD-aware decode: xcd = flat&7 owns 512 consecutive nids (8 (b,h) pairs)
    const int flat = blockIdx.x;
    const int nid = (flat & 7) * 512 + (flat >> 3);
    const int q0 = (nid & 63) * QBLK;
    const int h = (nid >> 6) & (NHEADS - 1);
    const int b = nid >> 9;

    const size_t base = (size_t)(b * NHEADS + h) * SEQ * DHEAD;
    const unsigned short* Qp = Q + base;
    const unsigned short* Kp = K + base;

    const int ks = w * 256;   // wave's key slice

    // ---- swapped QK^T with K prefetch ring (depth 4) ----
    const bf16x8 aq0 = *(const bf16x8*)(Qp + (size_t)(q0 + lr) * DHEAD + lg * 8);
    const bf16x8 aq1 = *(const bf16x8*)(Qp + (size_t)(q0 + lr) * DHEAD + 32 + lg * 8);
#define KROW(T) (Kp + (size_t)(ks + (T) * 16 + lr) * DHEAD + lg * 8)
    bf16x8 ka0 = *(const bf16x8*)KROW(0), kb0 = *(const bf16x8*)(KROW(0) + 32);
    bf16x8 ka1 = *(const bf16x8*)KROW(1), kb1 = *(const bf16x8*)(KROW(1) + 32);
    bf16x8 ka2 = *(const bf16x8*)KROW(2), kb2 = *(const bf16x8*)(KROW(2) + 32);
    bf16x8 ka3 = *(const bf16x8*)KROW(3), kb3 = *(const bf16x8*)(KROW(3) + 32);
    f32x4 acc[16];
#pragma unroll
    for (int t = 0; t < 16; ++t) acc[t] = (f32x4)0.f;
#define QK_STEP(T, KA, KB)                                                     \
    {                                                                          \
        acc[T] = __builtin_amdgcn_mfma_f32_16x16x32_bf16(KA, aq0, acc[T], 0, 0, 0); \
        acc[T] = __builtin_amdgcn_mfma_f32_16x16x32_bf16(KB, aq1, acc[T], 0, 0, 0); \
        if ((T) + 4 < 16) {                                                    \
            KA = *(const bf16x8*)KROW((T) + 4);                                \
            KB = *(const bf16x8*)(KROW((T) + 4) + 32);                         \
        }                                                                      \
    }
#pragma unroll
    for (int t = 0; t < 16; t += 4) {
        QK_STEP(t + 0, ka0, kb0)
        QK_STEP(t + 1, ka1, kb1)
        QK_STEP(t + 2, ka2, kb2)
        QK_STEP(t + 3, ka3, kb3)
    }
#undef QK_STEP
#undef KROW
    // lane (lr,lg) holds S[q-row q0+lr][key ks + t*16 + lg*4 + j]

    // ---- per-lane row max over 64 values, then lg-reduce (2 shfl stages) ----
    f32x4 m4 = acc[0];
#pragma unroll
    for (int t = 1; t < 16; ++t) {
        m4[0] = fmaxf(m4[0], acc[t][0]); m4[1] = fmaxf(m4[1], acc[t][1]);
        m4[2] = fmaxf(m4[2], acc[t][2]); m4[3] = fmaxf(m4[3], acc[t][3]);
    }
    float m = fmaxf(fmaxf(m4[0], m4[1]), fmaxf(m4[2], m4[3]));
    m = fmaxf(m, __shfl_xor(m, 16));
    m = fmaxf(m, __shfl_xor(m, 32));
    if (lg == 0) red_m[lr][w] = m;

    // clear candidate lists + counters (all threads)
    for (int i = tid; i < QBLK * 68; i += 256) (&clist[0][0])[i] = -3.0e38f;
    if (tid < QBLK) cnt_s[tid] = 0;
    __syncthreads();

    // block row max -> tau0 = max - 1 (f(tau0) >= 0, monotone Newton from below)
    const float4 rm4 = *(const float4*)red_m[lr];
    const float rmax = fmaxf(fmaxf(rm4.x, rm4.y), fmaxf(rm4.z, rm4.w));
    float tau = rmax - 1.0f;
    const float thr = tau;   // support is always a subset of {z > rowmax-1}

    // ---- candidate compaction (LDS atomics; cap 64/row, overflow->fallback) ----
#pragma unroll
    for (int t = 0; t < 16; ++t)
#pragma unroll
        for (int j = 0; j < 4; ++j) {
            const float z = acc[t][j];
            if (z > thr) {
                const int pos = atomicAdd(&cnt_s[lr], 1);
                if (pos < 64) clist[lr][pos] = z;
            }
        }
    __syncthreads();

    // block-uniform overflow check (cnt_s identical for all waves)
    const bool anyfull = __any(cnt_s[lr] > 64);

    if (!anyfull) {
        // ---- FAST PATH: zero barriers, zero LDS. Every wave computes the
        // identical row total from the shared candidate list. ----
        const f32x4* clp = (const f32x4*)&clist[lr][lg * 16];
        const f32x4 cd0 = clp[0], cd1 = clp[1], cd2 = clp[2], cd3 = clp[3];
        for (int it = 0; it < 16; ++it) {
            float s = 0.f, c = 0.f;
#pragma unroll
            for (int i = 0; i < 4; ++i) {
                const float z0 = cd0[i], z1 = cd1[i], z2 = cd2[i], z3 = cd3[i];
                if (z0 > tau) { s += z0; c += 1.f; }
                if (z1 > tau) { s += z1; c += 1.f; }
                if (z2 > tau) { s += z2; c += 1.f; }
                if (z3 > tau) { s += z3; c += 1.f; }
            }
            s += __shfl_xor(s, 16); c += __shfl_xor(c, 16);
            s += __shfl_xor(s, 32); c += __shfl_xor(c, 32);
            const float tn = (s - 1.f) / c;   // c >= 1 always (tau < row max)
            float delta = tn - tau;
            tau = tn;
            delta = fmaxf(delta, __shfl_xor(delta, 1));
            delta = fmaxf(delta, __shfl_xor(delta, 2));
            delta = fmaxf(delta, __shfl_xor(delta, 4));
            delta = fmaxf(delta, __shfl_xor(delta, 8));
            if (delta < 1e-5f) break;   // wave-uniform; same trajectory in all waves
        }
    } else {
        // ---- FALLBACK: full acc scan per wave slice + LDS cross-wave combine
        for (int it = 0; it < 16; ++it) {
            const int bb = (it + 1) & 1;
            float s = 0.f, c = 0.f;
#pragma unroll
            for (int t = 0; t < 16; ++t)
#pragma unroll
                for (int j = 0; j < 4; ++j) {
                    const float z = acc[t][j];
                    if (z > tau) { s += z; c += 1.f; }
                }
            s += __shfl_xor(s, 16); c += __shfl_xor(c, 16);
            s += __shfl_xor(s, 32); c += __shfl_xor(c, 32);
            if (lg == 0) { red_s[bb][lr][w] = s; red_c[bb][lr][w] = c; }
            __syncthreads();
            const float4 s4 = *(const float4*)red_s[bb][lr];
            const float4 c4 = *(const float4*)red_c[bb][lr];
            const float st = (s4.x + s4.y) + (s4.z + s4.w);
            const float ct = (c4.x + c4.y) + (c4.z + c4.w);
            const float tn = (st - 1.f) / ct;
            float delta = tn - tau;
            tau = tn;
            delta = fmaxf(delta, __shfl_xor(delta, 1));
            delta = fmaxf(delta, __shfl_xor(delta, 2));
            delta = fmaxf(delta, __shfl_xor(delta, 4));
            delta = fmaxf(delta, __shfl_xor(delta, 8));
            if (delta < 1e-5f) break;   // uniform across waves (same reduced values)
        }
    }

    // ---- P = relu(acc - tau) -> bf16 LDS, pair-packed b32 writes ----
#pragma unroll
    for (int t = 0; t < 16; ++t)
#pragma unroll
        for (int jp = 0; jp < 2; ++jp) {
            const unsigned lo = f2bf(fmaxf(acc[t][2 * jp] - tau, 0.f));
            const unsigned hi = f2bf(fmaxf(acc[t][2 * jp + 1] - tau, 0.f));
            *(unsigned*)&P[lr][ks + t * 16 + lg * 4 + 2 * jp] = lo | (hi << 16);
        }
    __syncthreads();   // P complete — last barrier

    // ---- PV: wave w owns d-cols w*16..+15; V from global Vt, depth-4 ring ----
    const int dcol = w * 16;
    const unsigned short* VtP = Vt + ((size_t)(b * NHEADS + h) * DHEAD + dcol + lr) * SEQ
                                + lg * 8;
    f32x4 o = (f32x4)0.f;
    bf16x8 vb0 = *(const bf16x8*)(VtP + 0 * 32);
    bf16x8 vb1 = *(const bf16x8*)(VtP + 1 * 32);
    bf16x8 vb2 = *(const bf16x8*)(VtP + 2 * 32);
    bf16x8 vb3 = *(const bf16x8*)(VtP + 3 * 32);
#define PV_STEP(KT, VREG)                                                      \
    {                                                                          \
        const bf16x8 pa = *(const bf16x8*)&P[lr][(KT) * 32 + lg * 8];          \
        __builtin_amdgcn_s_setprio(1);                                         \
        o = __builtin_amdgcn_mfma_f32_16x16x32_bf16(pa, VREG, o, 0, 0, 0);     \
        __builtin_amdgcn_s_setprio(0);                                         \
        if ((KT) + 4 < 32) VREG = *(const bf16x8*)(VtP + ((KT) + 4) * 32);     \
    }
    for (int kt = 0; kt < 32; kt += 4) {
        PV_STEP(kt + 0, vb0)
        PV_STEP(kt + 1, vb1)
        PV_STEP(kt + 2, vb2)
        PV_STEP(kt + 3, vb3)
    }
#undef PV_STEP

    // ---- write O tile rows q0+lg*4+j, cols h*64+dcol+lr (bf16 for final GEMM)
#pragma unroll
    for (int j = 0; j < 4; ++j)
        R[((size_t)b * SEQ + q0 + lg * 4 + j) * DMODEL + h * DHEAD + dcol + lr] =
            f2bf(o[j]);
}

extern "C" void kernel_launch(void* const* d_in, const int* in_sizes, int n_in,
                              void* d_out, int out_size, void* d_ws, size_t ws_size,
                              hipStream_t stream) {
    const float* h_q = (const float*)d_in[0];
    const float* h_k = (const float*)d_in[1];
    const float* h_v = (const float*)d_in[2];
    const float* Wq  = (const float*)d_in[3];
    const float* Wk  = (const float*)d_in[4];
    const float* Wv  = (const float*)d_in[5];
    const float* bv  = (const float*)d_in[6];
    const float* Wf  = (const float*)d_in[7];
    const float* bf  = (const float*)d_in[8];
    float* out = (float*)d_out;

    const size_t perT = (size_t)BS * SEQ * DMODEL;   // 4,194,304 elements
    const size_t wN = (size_t)DMODEL * DMODEL;       // 262,144 elements
    unsigned short* hq_b = (unsigned short*)d_ws;    // bf16 inputs
    unsigned short* hk_b = hq_b + perT;
    unsigned short* hv_b = hk_b + perT;
    unsigned short* Qws  = hv_b + perT;              // projections (head layout)
    unsigned short* Kws  = Qws + perT;
    unsigned short* Vtw  = Kws + perT;               // transposed [b][h][d][l]
    unsigned short* Rws  = Vtw + perT;               // attn output (bf16)
    unsigned short* Wqb  = Rws + perT;               // bf16 weights
    unsigned short* Wkb  = Wqb + wN;
    unsigned short* Wvb  = Wkb + wN;
    unsigned short* Wfb  = Wvb + wN;

    // 1) convert inputs + weights to bf16
    {
        CvtJob j0{h_q, hq_b, (int)(perT / 4)};
        CvtJob j1{h_k, hk_b, (int)(perT / 4)};
        CvtJob j2{h_v, hv_b, (int)(perT / 4)};
        CvtJob j3{Wq, Wqb, (int)(wN / 4)};
        CvtJob j4{Wk, Wkb, (int)(wN / 4)};
        CvtJob j5{Wv, Wvb, (int)(wN / 4)};
        CvtJob j6{Wf, Wfb, (int)(wN / 4)};
        cvt_many<<<dim3(512, 7), 256, 0, stream>>>(j0, j1, j2, j3, j4, j5, j6);
    }

    // 2) fused Q/K/V projections (bf16 MFMA, gload_lds staging)
    {
        GArgs gq{hq_b, Wqb, nullptr, Qws, 0.125f, 1};
        GArgs gk{hk_b, Wkb, nullptr, Kws, 1.0f, 1};
        GArgs gv{hv_b, Wvb, bv,      Vtw, 1.0f, 2};
        gemm_mfma<<<dim3(DMODEL / 128, BS * SEQ / 64, 3), 256, 0, stream>>>(gq, gk, gv);
    }

    // 3) attention
    attn_mfma<<<dim3(BS * NHEADS * (SEQ / QBLK)), 256, 0, stream>>>(Qws, Kws, Vtw, Rws);

    // 4) output projection
    {
        GArgs gf{Rws, Wfb, bf, out, 1.0f, 0};
        gemm_mfma<<<dim3(DMODEL / 128, BS * SEQ / 64, 1), 256, 0, stream>>>(gf, gf, gf);
    }
}

// Round 11
// 190.585 us; speedup vs baseline: 1.0300x; 1.0117x over previous
//
#include <hip/hip_runtime.h>
#include <hip/hip_bf16.h>
#include <cstdint>
#include <cstddef>

#define BS 8
#define SEQ 1024
#define DMODEL 512
#define NHEADS 8
#define DHEAD 64
#define QBLK 16
#define PPAD 1032   // P bf16 row stride (elems); dense-fallback only

typedef float f32x4 __attribute__((ext_vector_type(4)));
typedef short bf16x8 __attribute__((ext_vector_type(8)));

static __device__ __forceinline__ unsigned short f2bf(float v) {
    __hip_bfloat16 hb = __float2bfloat16(v);
    return *reinterpret_cast<unsigned short*>(&hb);
}

// ---------------------------------------------------------------------------
// f32 -> bf16 conversion pre-pass (7 independent jobs, blockIdx.y selects)
// ---------------------------------------------------------------------------
struct CvtJob { const float* s; unsigned short* d; int n4; };

__global__ __launch_bounds__(256) void cvt_many(
    CvtJob j0, CvtJob j1, CvtJob j2, CvtJob j3, CvtJob j4, CvtJob j5, CvtJob j6)
{
    CvtJob j;
    switch (blockIdx.y) {
        case 0: j = j0; break; case 1: j = j1; break; case 2: j = j2; break;
        case 3: j = j3; break; case 4: j = j4; break; case 5: j = j5; break;
        default: j = j6; break;
    }
    for (int i = blockIdx.x * 256 + threadIdx.x; i < j.n4; i += gridDim.x * 256) {
        const float4 f = ((const float4*)j.s)[i];
        uint2 u;
        u.x = (unsigned)f2bf(f.x) | ((unsigned)f2bf(f.y) << 16);
        u.y = (unsigned)f2bf(f.z) | ((unsigned)f2bf(f.w) << 16);
        ((uint2*)j.d)[i] = u;
    }
}

// ---------------------------------------------------------------------------
// bf16 MFMA GEMM, tile 64M x 128N, BK=64, global_load_lds + XOR source-swizzle.
// Modes: 0 f32 [M][512]+bias; 1 bf16 head layout [b][h][l][dd] (*scale,+bias);
// 2 bf16 transposed [b][h][dd][l]; 3 = mode1 to C AND mode2 to C2 (V dual).
// ---------------------------------------------------------------------------
struct GArgs { const unsigned short* A; const unsigned short* W;
               const float* bias; void* C; void* C2; float scale; int mode; };

__global__ __launch_bounds__(256) void gemm_mfma(GArgs g0, GArgs g1, GArgs g2) {
    __shared__ __align__(16) unsigned short As[64 * 64];
    __shared__ __align__(16) unsigned short Bs[128 * 64];

    const GArgs g = (blockIdx.z == 0) ? g0 : ((blockIdx.z == 1) ? g1 : g2);
    const int tid = threadIdx.x;
    const int w = tid >> 6, l = tid & 63, lr = l & 15, lg = l >> 4;
    const int bm = blockIdx.y * 64, bn = blockIdx.x * 128;
    const int mrow = (w & 1) * 32, ncol = (w >> 1) * 64;

    f32x4 acc[2][4];
#pragma unroll
    for (int mt = 0; mt < 2; ++mt)
#pragma unroll
        for (int nt = 0; nt < 4; ++nt) acc[mt][nt] = (f32x4)0.f;

    for (int k0 = 0; k0 < DMODEL; k0 += 64) {
#pragma unroll
        for (int i = 0; i < 2; ++i) {
            const int rbase = i * 32 + w * 8;
            const int r = rbase + (l >> 3);
            const unsigned short* src = g.A + (size_t)(bm + r) * DMODEL + k0
                                        + 8 * ((l & 7) ^ (r & 7));
            __builtin_amdgcn_global_load_lds((const unsigned int*)src,
                                             (unsigned int*)&As[rbase * 64], 16, 0, 0);
        }
#pragma unroll
        for (int i = 0; i < 4; ++i) {
            const int rbase = i * 32 + w * 8;
            const int r = rbase + (l >> 3);
            const unsigned short* src = g.W + (size_t)(bn + r) * DMODEL + k0
                                        + 8 * ((l & 7) ^ (r & 7));
            __builtin_amdgcn_global_load_lds((const unsigned int*)src,
                                             (unsigned int*)&Bs[rbase * 64], 16, 0, 0);
        }
        __syncthreads();
#pragma unroll
        for (int kk = 0; kk < 2; ++kk) {
            bf16x8 av[2], bv[4];
#pragma unroll
            for (int mt = 0; mt < 2; ++mt) {
                const int ra = mrow + mt * 16 + lr;
                av[mt] = *(const bf16x8*)&As[ra * 64 + 8 * ((kk * 4 + lg) ^ (ra & 7))];
            }
#pragma unroll
            for (int nt = 0; nt < 4; ++nt) {
                const int rb = ncol + nt * 16 + lr;
                bv[nt] = *(const bf16x8*)&Bs[rb * 64 + 8 * ((kk * 4 + lg) ^ (rb & 7))];
            }
#pragma unroll
            for (int mt = 0; mt < 2; ++mt)
#pragma unroll
                for (int nt = 0; nt < 4; ++nt)
                    acc[mt][nt] = __builtin_amdgcn_mfma_f32_16x16x32_bf16(
                        av[mt], bv[nt], acc[mt][nt], 0, 0, 0);
        }
        __syncthreads();
    }

    if (g.mode == 0) {
        float* C = (float*)g.C;
#pragma unroll
        for (int mt = 0; mt < 2; ++mt)
#pragma unroll
        for (int nt = 0; nt < 4; ++nt)
#pragma unroll
        for (int j = 0; j < 4; ++j) {
            const int r = bm + mrow + mt * 16 + lg * 4 + j;
            const int c = bn + ncol + nt * 16 + lr;
            C[(size_t)r * DMODEL + c] = acc[mt][nt][j] * g.scale
                                        + (g.bias ? g.bias[c] : 0.f);
        }
    } else {
        if (g.mode == 1 || g.mode == 3) {
            unsigned short* C = (unsigned short*)g.C;
#pragma unroll
            for (int mt = 0; mt < 2; ++mt)
#pragma unroll
            for (int nt = 0; nt < 4; ++nt)
#pragma unroll
            for (int j = 0; j < 4; ++j) {
                const int r = bm + mrow + mt * 16 + lg * 4 + j;
                const int c = bn + ncol + nt * 16 + lr;
                const float v = acc[mt][nt][j] * g.scale + (g.bias ? g.bias[c] : 0.f);
                const int b = r >> 10, ll = r & (SEQ - 1);
                const int h = c >> 6, dd = c & 63;
                C[((size_t)(b * NHEADS + h) * SEQ + ll) * DHEAD + dd] = f2bf(v);
            }
        }
        if (g.mode == 2 || g.mode == 3) {
            unsigned short* C = (unsigned short*)((g.mode == 3) ? g.C2 : g.C);
#pragma unroll
            for (int mt = 0; mt < 2; ++mt)
#pragma unroll
            for (int nt = 0; nt < 4; ++nt) {
                const int c = bn + ncol + nt * 16 + lr;
                const int h = c >> 6, dd = c & 63;
                const int r0 = bm + mrow + mt * 16 + lg * 4;
                const int b = r0 >> 10, l0 = r0 & (SEQ - 1);
                unsigned short tmp[4];
#pragma unroll
                for (int j = 0; j < 4; ++j)
                    tmp[j] = f2bf(acc[mt][nt][j] * g.scale + (g.bias ? g.bias[c] : 0.f));
                uint2 u;
                u.x = (unsigned)tmp[0] | ((unsigned)tmp[1] << 16);
                u.y = (unsigned)tmp[2] | ((unsigned)tmp[3] << 16);
                *(uint2*)&C[((size_t)(b * NHEADS + h) * DHEAD + dd) * SEQ + l0] = u;
            }
        }
    }
}

// ---------------------------------------------------------------------------
// MFMA sparsemax attention with SPARSE PV (r11).
// Front half (r10-validated): swapped QK^T reg-resident, rowmax, candidate
// compaction (now with INDICES), wave-local Newton.
// Back half: sparsemax support ⊆ candidates, so PV = gather-MAC over ≤64
// candidates per row (typ. ~14) from normal-layout V — no P, no dense MFMA.
// Fallback (block-uniform, any row's list overflows): r10 dense path (P LDS
// + MFMA PV from Vt). Correctness unconditional.
// ---------------------------------------------------------------------------
__global__ __launch_bounds__(256, 4) void attn_mfma(
    const unsigned short* __restrict__ Q, const unsigned short* __restrict__ K,
    const unsigned short* __restrict__ Vt, const unsigned short* __restrict__ Vn,
    unsigned short* __restrict__ R)
{
    __shared__ __align__(16) unsigned short P[QBLK][PPAD];     // 33 KB (fallback)
    __shared__ __align__(16) float clist[QBLK][66];            // candidate values
    __shared__ __align__(16) unsigned short cidx[QBLK][66];    // candidate key idx
    __shared__ int cnt_s[QBLK];
    __shared__ __align__(16) float red_m[QBLK][4];
    __shared__ __align__(16) float red_s[2][QBLK][4];
    __shared__ __align__(16) float red_c[2][QBLK][4];
    __shared__ float tau_s[QBLK];

    const int tid = threadIdx.x;
    const int w = tid >> 6, l = tid & 63, lr = l & 15, lg = l >> 4;

    // XCD-aware decode
    const int flat = blockIdx.x;
    const int nid = (flat & 7) * 512 + (flat >> 3);
    const int q0 = (nid & 63) * QBLK;
    const int h = (nid >> 6) & (NHEADS - 1);
    const int b = nid >> 9;

    const size_t base = (size_t)(b * NHEADS + h) * SEQ * DHEAD;
    const unsigned short* Qp = Q + base;
    const unsigned short* Kp = K + base;

    const int ks = w * 256;

    // ---- swapped QK^T with K prefetch ring (depth 4) ----
    const bf16x8 aq0 = *(const bf16x8*)(Qp + (size_t)(q0 + lr) * DHEAD + lg * 8);
    const bf16x8 aq1 = *(const bf16x8*)(Qp + (size_t)(q0 + lr) * DHEAD + 32 + lg * 8);
#define KROW(T) (Kp + (size_t)(ks + (T) * 16 + lr) * DHEAD + lg * 8)
    bf16x8 ka0 = *(const bf16x8*)KROW(0), kb0 = *(const bf16x8*)(KROW(0) + 32);
    bf16x8 ka1 = *(const bf16x8*)KROW(1), kb1 = *(const bf16x8*)(KROW(1) + 32);
    bf16x8 ka2 = *(const bf16x8*)KROW(2), kb2 = *(const bf16x8*)(KROW(2) + 32);
    bf16x8 ka3 = *(const bf16x8*)KROW(3), kb3 = *(const bf16x8*)(KROW(3) + 32);
    f32x4 acc[16];
#pragma unroll
    for (int t = 0; t < 16; ++t) acc[t] = (f32x4)0.f;
#define QK_STEP(T, KA, KB)                                                     \
    {                                                                          \
        acc[T] = __builtin_amdgcn_mfma_f32_16x16x32_bf16(KA, aq0, acc[T], 0, 0, 0); \
        acc[T] = __builtin_amdgcn_mfma_f32_16x16x32_bf16(KB, aq1, acc[T], 0, 0, 0); \
        if ((T) + 4 < 16) {                                                    \
            KA = *(const bf16x8*)KROW((T) + 4);                                \
            KB = *(const bf16x8*)(KROW((T) + 4) + 32);                         \
        }                                                                      \
    }
#pragma unroll
    for (int t = 0; t < 16; t += 4) {
        QK_STEP(t + 0, ka0, kb0)
        QK_STEP(t + 1, ka1, kb1)
        QK_STEP(t + 2, ka2, kb2)
        QK_STEP(t + 3, ka3, kb3)
    }
#undef QK_STEP
#undef KROW
    // lane (lr,lg) holds S[q-row q0+lr][key ks + t*16 + lg*4 + j]

    // ---- row max ----
    f32x4 m4 = acc[0];
#pragma unroll
    for (int t = 1; t < 16; ++t) {
        m4[0] = fmaxf(m4[0], acc[t][0]); m4[1] = fmaxf(m4[1], acc[t][1]);
        m4[2] = fmaxf(m4[2], acc[t][2]); m4[3] = fmaxf(m4[3], acc[t][3]);
    }
    float m = fmaxf(fmaxf(m4[0], m4[1]), fmaxf(m4[2], m4[3]));
    m = fmaxf(m, __shfl_xor(m, 16));
    m = fmaxf(m, __shfl_xor(m, 32));
    if (lg == 0) red_m[lr][w] = m;

    // clear candidate lists + counters
    for (int i = tid; i < QBLK * 66; i += 256) (&clist[0][0])[i] = -3.0e38f;
    if (tid < QBLK) cnt_s[tid] = 0;
    __syncthreads();

    const float4 rm4 = *(const float4*)red_m[lr];
    const float rmax = fmaxf(fmaxf(rm4.x, rm4.y), fmaxf(rm4.z, rm4.w));
    float tau = rmax - 1.0f;
    const float thr = tau;   // support subset of {z > rowmax-1}

    // ---- candidate compaction with indices (cap 64) ----
#pragma unroll
    for (int t = 0; t < 16; ++t)
#pragma unroll
        for (int j = 0; j < 4; ++j) {
            const float z = acc[t][j];
            if (z > thr) {
                const int pos = atomicAdd(&cnt_s[lr], 1);
                if (pos < 64) {
                    clist[lr][pos] = z;
                    cidx[lr][pos] = (unsigned short)(ks + t * 16 + lg * 4 + j);
                }
            }
        }
    __syncthreads();

    const bool anyfull = __any(cnt_s[lr] > 64);   // block-uniform

    if (!anyfull) {
        // ---- FAST: wave-local Newton on shared candidate list ----
        const f32x4* clp = (const f32x4*)&clist[lr][lg * 16];
        const f32x4 cd0 = clp[0], cd1 = clp[1], cd2 = clp[2], cd3 = clp[3];
        for (int it = 0; it < 16; ++it) {
            float s = 0.f, c = 0.f;
#pragma unroll
            for (int i = 0; i < 4; ++i) {
                const float z0 = cd0[i], z1 = cd1[i], z2 = cd2[i], z3 = cd3[i];
                if (z0 > tau) { s += z0; c += 1.f; }
                if (z1 > tau) { s += z1; c += 1.f; }
                if (z2 > tau) { s += z2; c += 1.f; }
                if (z3 > tau) { s += z3; c += 1.f; }
            }
            s += __shfl_xor(s, 16); c += __shfl_xor(c, 16);
            s += __shfl_xor(s, 32); c += __shfl_xor(c, 32);
            const float tn = (s - 1.f) / c;
            float delta = tn - tau;
            tau = tn;
            delta = fmaxf(delta, __shfl_xor(delta, 1));
            delta = fmaxf(delta, __shfl_xor(delta, 2));
            delta = fmaxf(delta, __shfl_xor(delta, 4));
            delta = fmaxf(delta, __shfl_xor(delta, 8));
            if (delta < 1e-5f) break;
        }
        if (w == 0 && lg == 0) tau_s[lr] = tau;
        __syncthreads();

        // ---- SPARSE PV: thread (r, dt) = (tid>>4, tid&15), gather-MAC ----
        const int r = tid >> 4;
        const int dt = tid & 15;
        const float taur = tau_s[r];
        const int cntc = cnt_s[r];   // >= 1 always (rowmax candidate)
        const unsigned short* Vrow = Vn + base + dt * 4;
        f32x4 o = (f32x4)0.f;
        float z0, z1, z2, z3;
        uint2 v0, v1, v2, v3;
#define SLOAD(ZS, VS, I)                                                       \
    {                                                                          \
        const int ii = (I) < cntc ? (I) : 0;                                   \
        ZS = clist[r][ii];                                                     \
        VS = *(const uint2*)(Vrow + (size_t)cidx[r][ii] * DHEAD);              \
    }
#define SMAC(ZS, VS)                                                           \
    {                                                                          \
        const float wgt = fmaxf(ZS - taur, 0.f);                               \
        o[0] += wgt * __uint_as_float(VS.x << 16);                             \
        o[1] += wgt * __uint_as_float(VS.x & 0xffff0000u);                     \
        o[2] += wgt * __uint_as_float(VS.y << 16);                             \
        o[3] += wgt * __uint_as_float(VS.y & 0xffff0000u);                     \
    }
        SLOAD(z0, v0, 0) SLOAD(z1, v1, 1) SLOAD(z2, v2, 2) SLOAD(z3, v3, 3)
        for (int i = 0; i < cntc; i += 4) {
            SMAC(z0, v0)
            if (i + 1 < cntc) SMAC(z1, v1)
            if (i + 2 < cntc) SMAC(z2, v2)
            if (i + 3 < cntc) SMAC(z3, v3)
            SLOAD(z0, v0, i + 4) SLOAD(z1, v1, i + 5)
            SLOAD(z2, v2, i + 6) SLOAD(z3, v3, i + 7)
        }
#undef SLOAD
#undef SMAC
        unsigned short t4[4];
#pragma unroll
        for (int j = 0; j < 4; ++j) t4[j] = f2bf(o[j]);
        uint2 u;
        u.x = (unsigned)t4[0] | ((unsigned)t4[1] << 16);
        u.y = (unsigned)t4[2] | ((unsigned)t4[3] << 16);
        *(uint2*)&R[((size_t)b * SEQ + q0 + r) * DMODEL + h * DHEAD + dt * 4] = u;
        return;
    }

    // ================= DENSE FALLBACK (r10 path, unconditional-correct) =====
    for (int it = 0; it < 16; ++it) {
        const int bb = (it + 1) & 1;
        float s = 0.f, c = 0.f;
#pragma unroll
        for (int t = 0; t < 16; ++t)
#pragma unroll
            for (int j = 0; j < 4; ++j) {
                const float z = acc[t][j];
                if (z > tau) { s += z; c += 1.f; }
            }
        s += __shfl_xor(s, 16); c += __shfl_xor(c, 16);
        s += __shfl_xor(s, 32); c += __shfl_xor(c, 32);
        if (lg == 0) { red_s[bb][lr][w] = s; red_c[bb][lr][w] = c; }
        __syncthreads();
        const float4 s4 = *(const float4*)red_s[bb][lr];
        const float4 c4 = *(const float4*)red_c[bb][lr];
        const float st = (s4.x + s4.y) + (s4.z + s4.w);
        const float ct = (c4.x + c4.y) + (c4.z + c4.w);
        const float tn = (st - 1.f) / ct;
        float delta = tn - tau;
        tau = tn;
        delta = fmaxf(delta, __shfl_xor(delta, 1));
        delta = fmaxf(delta, __shfl_xor(delta, 2));
        delta = fmaxf(delta, __shfl_xor(delta, 4));
        delta = fmaxf(delta, __shfl_xor(delta, 8));
        if (delta < 1e-5f) break;
    }

#pragma unroll
    for (int t = 0; t < 16; ++t)
#pragma unroll
        for (int jp = 0; jp < 2; ++jp) {
            const unsigned lo = f2bf(fmaxf(acc[t][2 * jp] - tau, 0.f));
            const unsigned hi = f2bf(fmaxf(acc[t][2 * jp + 1] - tau, 0.f));
            *(unsigned*)&P[lr][ks + t * 16 + lg * 4 + 2 * jp] = lo | (hi << 16);
        }
    __syncthreads();

    const int dcol = w * 16;
    const unsigned short* VtP = Vt + ((size_t)(b * NHEADS + h) * DHEAD + dcol + lr) * SEQ
                                + lg * 8;
    f32x4 o = (f32x4)0.f;
    bf16x8 vb0 = *(const bf16x8*)(VtP + 0 * 32);
    bf16x8 vb1 = *(const bf16x8*)(VtP + 1 * 32);
    bf16x8 vb2 = *(const bf16x8*)(VtP + 2 * 32);
    bf16x8 vb3 = *(const bf16x8*)(VtP + 3 * 32);
#define PV_STEP(KT, VREG)                                                      \
    {                                                                          \
        const bf16x8 pa = *(const bf16x8*)&P[lr][(KT) * 32 + lg * 8];          \
        o = __builtin_amdgcn_mfma_f32_16x16x32_bf16(pa, VREG, o, 0, 0, 0);     \
        if ((KT) + 4 < 32) VREG = *(const bf16x8*)(VtP + ((KT) + 4) * 32);     \
    }
    for (int kt = 0; kt < 32; kt += 4) {
        PV_STEP(kt + 0, vb0)
        PV_STEP(kt + 1, vb1)
        PV_STEP(kt + 2, vb2)
        PV_STEP(kt + 3, vb3)
    }
#undef PV_STEP

#pragma unroll
    for (int j = 0; j < 4; ++j)
        R[((size_t)b * SEQ + q0 + lg * 4 + j) * DMODEL + h * DHEAD + dcol + lr] =
            f2bf(o[j]);
}

extern "C" void kernel_launch(void* const* d_in, const int* in_sizes, int n_in,
                              void* d_out, int out_size, void* d_ws, size_t ws_size,
                              hipStream_t stream) {
    const float* h_q = (const float*)d_in[0];
    const float* h_k = (const float*)d_in[1];
    const float* h_v = (const float*)d_in[2];
    const float* Wq  = (const float*)d_in[3];
    const float* Wk  = (const float*)d_in[4];
    const float* Wv  = (const float*)d_in[5];
    const float* bv  = (const float*)d_in[6];
    const float* Wf  = (const float*)d_in[7];
    const float* bf  = (const float*)d_in[8];
    float* out = (float*)d_out;

    const size_t perT = (size_t)BS * SEQ * DMODEL;   // 4,194,304 elements
    const size_t wN = (size_t)DMODEL * DMODEL;
    unsigned short* hq_b = (unsigned short*)d_ws;
    unsigned short* hk_b = hq_b + perT;
    unsigned short* hv_b = hk_b + perT;
    unsigned short* Qws  = hv_b + perT;              // head layout, pre-scaled
    unsigned short* Kws  = Qws + perT;               // head layout
    unsigned short* Vtw  = Kws + perT;               // transposed [b][h][d][l]
    unsigned short* Vnw  = Vtw + perT;               // normal head layout [b][h][l][d]
    unsigned short* Rws  = Vnw + perT;               // attn output (bf16)
    unsigned short* Wqb  = Rws + perT;
    unsigned short* Wkb  = Wqb + wN;
    unsigned short* Wvb  = Wkb + wN;
    unsigned short* Wfb  = Wvb + wN;

    // 1) convert inputs + weights to bf16
    {
        CvtJob j0{h_q, hq_b, (int)(perT / 4)};
        CvtJob j1{h_k, hk_b, (int)(perT / 4)};
        CvtJob j2{h_v, hv_b, (int)(perT / 4)};
        CvtJob j3{Wq, Wqb, (int)(wN / 4)};
        CvtJob j4{Wk, Wkb, (int)(wN / 4)};
        CvtJob j5{Wv, Wvb, (int)(wN / 4)};
        CvtJob j6{Wf, Wfb, (int)(wN / 4)};
        cvt_many<<<dim3(512, 7), 256, 0, stream>>>(j0, j1, j2, j3, j4, j5, j6);
    }

    // 2) fused Q/K/V projections (V in BOTH layouts: normal + transposed)
    {
        GArgs gq{hq_b, Wqb, nullptr, Qws, nullptr, 0.125f, 1};
        GArgs gk{hk_b, Wkb, nullptr, Kws, nullptr, 1.0f, 1};
        GArgs gv{hv_b, Wvb, bv,      Vnw, Vtw,     1.0f, 3};
        gemm_mfma<<<dim3(DMODEL / 128, BS * SEQ / 64, 3), 256, 0, stream>>>(gq, gk, gv);
    }

    // 3) attention (sparse PV fast path, dense MFMA fallback)
    attn_mfma<<<dim3(BS * NHEADS * (SEQ / QBLK)), 256, 0, stream>>>(Qws, Kws, Vtw, Vnw, Rws);

    // 4) output projection
    {
        GArgs gf{Rws, Wfb, bf, out, nullptr, 1.0f, 0};
        gemm_mfma<<<dim3(DMODEL / 128, BS * SEQ / 64, 1), 256, 0, stream>>>(gf, gf, gf);
    }
}